// Round 1
// baseline (159.428 us; speedup 1.0000x reference)
//
#include <hip/hip_runtime.h>
#include <hip/hip_bf16.h>
#include <cstdint>

#define M_DIM 2048
#define K_DIM 4096
#define N_DIM 4096

typedef __attribute__((ext_vector_type(8))) short bf16x8;
typedef __attribute__((ext_vector_type(4))) float f32x4;
typedef unsigned short u16;

// ---- async global->LDS, 16B per lane (dest = wave-uniform base + lane*16) ----
__device__ __forceinline__ void gload_lds16(const void* g, void* l) {
  __builtin_amdgcn_global_load_lds(
      (__attribute__((address_space(1))) void*)(g),
      (__attribute__((address_space(3))) void*)(l), 16, 0, 0);
}

// fp32 (holding a small-integer value) -> bf16 bits; exact for |v|<=256 ints
__device__ __forceinline__ u16 f32_to_bf16_bits(float f) {
  return (u16)(__float_as_uint(f) >> 16);
}

// ============================================================================
// K1: per-row RMS sum-of-squares (double), per-row inv_rms, global absmax of
//     normalized activations (atomicMax on float bits; all values >= 0).
// ============================================================================
__global__ void rms_absmax_kernel(const float* __restrict__ x,
                                  const float* __restrict__ rw,
                                  float* __restrict__ invrms,
                                  unsigned* __restrict__ absmax_bits) {
  const int row = blockIdx.x;
  const int tid = threadIdx.x;
  const float4* xr = (const float4*)(x + (size_t)row * K_DIM);
  const float4* wr = (const float4*)rw;

  float4 xv[4];
  double ss = 0.0;
#pragma unroll
  for (int i = 0; i < 4; i++) {
    xv[i] = xr[i * 256 + tid];
    ss += (double)xv[i].x * xv[i].x + (double)xv[i].y * xv[i].y +
          (double)xv[i].z * xv[i].z + (double)xv[i].w * xv[i].w;
  }
  __shared__ double red[4];
  __shared__ float redf[4];
  __shared__ float sInv;
  for (int off = 32; off; off >>= 1) ss += __shfl_down(ss, off);
  if ((tid & 63) == 0) red[tid >> 6] = ss;
  __syncthreads();
  if (tid == 0) {
    double t = red[0] + red[1] + red[2] + red[3];
    double inv = 1.0 / sqrt(t * (1.0 / (double)K_DIM) + 1e-6);
    sInv = (float)inv;
  }
  __syncthreads();
  const float inv = sInv;
  if (tid == 0) invrms[row] = inv;

  float amax = 0.f;
#pragma unroll
  for (int i = 0; i < 4; i++) {
    float4 wv = wr[i * 256 + tid];
    amax = fmaxf(amax, fabsf(xv[i].x * inv * wv.x));
    amax = fmaxf(amax, fabsf(xv[i].y * inv * wv.y));
    amax = fmaxf(amax, fabsf(xv[i].z * inv * wv.z));
    amax = fmaxf(amax, fabsf(xv[i].w * inv * wv.w));
  }
  for (int off = 32; off; off >>= 1) amax = fmaxf(amax, __shfl_down(amax, off));
  if ((tid & 63) == 0) redf[tid >> 6] = amax;
  __syncthreads();
  if (tid == 0) {
    float m = fmaxf(fmaxf(redf[0], redf[1]), fmaxf(redf[2], redf[3]));
    atomicMax(absmax_bits, __float_as_uint(m));  // floats >= 0: bit-order == value-order
  }
}

// ============================================================================
// K2a/K2b: deterministic two-stage double-precision sum of |W| (16.8M elems)
// ============================================================================
__global__ void wsum_partial_kernel(const float* __restrict__ w,
                                    double* __restrict__ partials) {
  const int tid = threadIdx.x;
  const int bid = blockIdx.x;
  const float4* w4 = (const float4*)w;
  const size_t base = (size_t)bid * 2048;
  double s = 0.0;
#pragma unroll
  for (int i = 0; i < 8; i++) {
    float4 v = w4[base + i * 256 + tid];
    s += (double)fabsf(v.x) + (double)fabsf(v.y) + (double)fabsf(v.z) + (double)fabsf(v.w);
  }
  for (int off = 32; off; off >>= 1) s += __shfl_down(s, off);
  __shared__ double red[4];
  if ((tid & 63) == 0) red[tid >> 6] = s;
  __syncthreads();
  if (tid == 0) partials[bid] = red[0] + red[1] + red[2] + red[3];
}

__global__ void wsum_final_kernel(const double* __restrict__ partials,
                                  double* __restrict__ wsum) {
  const int tid = threadIdx.x;
  double s = 0.0;
#pragma unroll
  for (int i = 0; i < 8; i++) s += partials[i * 256 + tid];
  for (int off = 32; off; off >>= 1) s += __shfl_down(s, off);
  __shared__ double red[4];
  if ((tid & 63) == 0) red[tid >> 6] = s;
  __syncthreads();
  if (tid == 0) *wsum = red[0] + red[1] + red[2] + red[3];
}

// ============================================================================
// K3: quantize activations: A_q = clip(rint(xn * a_scale), -128, 127) as bf16
//     (xn recomputed with the SAME fp32 expression as K1's absmax pass)
// ============================================================================
__global__ void aquant_kernel(const float* __restrict__ x,
                              const float* __restrict__ rw,
                              const float* __restrict__ invrms,
                              const unsigned* __restrict__ absmax_bits,
                              u16* __restrict__ Aq) {
  const int row = blockIdx.x;
  const int tid = threadIdx.x;
  const float inv = invrms[row];
  const double a_scale = 127.0 / fmax((double)__uint_as_float(*absmax_bits), 1e-5);
  const float4* xr = (const float4*)(x + (size_t)row * K_DIM);
  const float4* wr = (const float4*)rw;
  ushort4* Ar = (ushort4*)(Aq + (size_t)row * K_DIM);
#pragma unroll
  for (int i = 0; i < 4; i++) {
    const int idx = i * 256 + tid;
    float4 xv = xr[idx];
    float4 wv = wr[idx];
    ushort4 o;
    {
      double v = fmin(fmax(rint((double)(xv.x * inv * wv.x) * a_scale), -128.0), 127.0);
      o.x = f32_to_bf16_bits((float)v);
    }
    {
      double v = fmin(fmax(rint((double)(xv.y * inv * wv.y) * a_scale), -128.0), 127.0);
      o.y = f32_to_bf16_bits((float)v);
    }
    {
      double v = fmin(fmax(rint((double)(xv.z * inv * wv.z) * a_scale), -128.0), 127.0);
      o.z = f32_to_bf16_bits((float)v);
    }
    {
      double v = fmin(fmax(rint((double)(xv.w * inv * wv.w) * a_scale), -128.0), 127.0);
      o.w = f32_to_bf16_bits((float)v);
    }
    Ar[idx] = o;
  }
}

// ============================================================================
// K4: ternary-quantize weight AND transpose: Bt[n][k] = clip(rint(W[k][n]*b_scale),-1,1)
//     64x64 tile through padded LDS so both global read and write are coalesced.
// ============================================================================
__global__ void wquant_kernel(const float* __restrict__ w,
                              const double* __restrict__ wsum,
                              u16* __restrict__ Bt) {
  __shared__ float lds[64][65];
  const int tid = threadIdx.x;
  const int n0 = blockIdx.x * 64;
  const int k0 = blockIdx.y * 64;
  const double wmean = *wsum * (1.0 / 16777216.0);
  const double bs = 1.0 / fmax(wmean, 1e-5);
#pragma unroll
  for (int i = 0; i < 4; i++) {
    const int id = i * 256 + tid;     // 0..1023
    const int r = id >> 4;            // k-row in tile
    const int c4 = (id & 15) * 4;     // n-col in tile
    float4 v = *(const float4*)(w + (size_t)(k0 + r) * N_DIM + n0 + c4);
    lds[c4 + 0][r] = (float)fmin(fmax(rint((double)v.x * bs), -1.0), 1.0);
    lds[c4 + 1][r] = (float)fmin(fmax(rint((double)v.y * bs), -1.0), 1.0);
    lds[c4 + 2][r] = (float)fmin(fmax(rint((double)v.z * bs), -1.0), 1.0);
    lds[c4 + 3][r] = (float)fmin(fmax(rint((double)v.w * bs), -1.0), 1.0);
  }
  __syncthreads();
#pragma unroll
  for (int i = 0; i < 4; i++) {
    const int id = i * 256 + tid;
    const int rn = id >> 4;           // n-row of Bt tile
    const int c4 = (id & 15) * 4;     // k-col of Bt tile
    ushort4 o;
    o.x = f32_to_bf16_bits(lds[rn][c4 + 0]);
    o.y = f32_to_bf16_bits(lds[rn][c4 + 1]);
    o.z = f32_to_bf16_bits(lds[rn][c4 + 2]);
    o.w = f32_to_bf16_bits(lds[rn][c4 + 3]);
    *(ushort4*)(Bt + (size_t)(n0 + rn) * K_DIM + k0 + c4) = o;
  }
}

// ============================================================================
// K5: GEMM, m97 structure: 128x128 tile, BK=32, 4 waves (2x2) of 64x64 each,
//     global_load_lds width=16, 16x16x32 bf16 MFMA, fp32 accumulate (exact
//     for these integer-valued operands). Epilogue dequant by 1/(as*bs).
// ============================================================================
__global__ void gemm_kernel(const u16* __restrict__ Aq, const u16* __restrict__ Bt,
                            float* __restrict__ out,
                            const unsigned* __restrict__ absmax_bits,
                            const double* __restrict__ wsum) {
  __shared__ u16 As[128 * 32];
  __shared__ u16 Bs[128 * 32];
  const int tid = threadIdx.x;
  const int lane = tid & 63;
  const int wave = tid >> 6;
  const int wm = wave >> 1, wn = wave & 1;
  const int brow = blockIdx.y * 128;
  const int bcol = blockIdx.x * 128;

  f32x4 acc[4][4];
#pragma unroll
  for (int m = 0; m < 4; m++)
#pragma unroll
    for (int n = 0; n < 4; n++) acc[m][n] = {0.f, 0.f, 0.f, 0.f};

  const int srow = lane >> 2;        // 0..15
  const int scol = (lane & 3) * 8;   // 0,8,16,24

  for (int k0 = 0; k0 < K_DIM; k0 += 32) {
    // ---- stage A,B tiles: 8 chunks each of (16 rows x 32 cols) = 1KB/wave-op
#pragma unroll
    for (int i = 0; i < 2; i++) {
      const int chunk = i * 4 + wave;  // wave-uniform
      const u16* ga = Aq + (size_t)(brow + chunk * 16 + srow) * K_DIM + k0 + scol;
      gload_lds16(ga, As + chunk * 512);
      const u16* gb = Bt + (size_t)(bcol + chunk * 16 + srow) * K_DIM + k0 + scol;
      gload_lds16(gb, Bs + chunk * 512);
    }
    __syncthreads();  // drains vmcnt(0): loads landed

    bf16x8 a[4], b[4];
#pragma unroll
    for (int m = 0; m < 4; m++) {
      const int ar = wm * 64 + m * 16 + (lane & 15);
      a[m] = *(const bf16x8*)(As + ar * 32 + (lane >> 4) * 8);
    }
#pragma unroll
    for (int n = 0; n < 4; n++) {
      const int br = wn * 64 + n * 16 + (lane & 15);
      b[n] = *(const bf16x8*)(Bs + br * 32 + (lane >> 4) * 8);
    }
#pragma unroll
    for (int m = 0; m < 4; m++)
#pragma unroll
      for (int n = 0; n < 4; n++)
        acc[m][n] = __builtin_amdgcn_mfma_f32_16x16x32_bf16(a[m], b[n], acc[m][n], 0, 0, 0);
    __syncthreads();  // compute done before next stage overwrites
  }

  const float amax = __uint_as_float(*absmax_bits);
  const double a_scale = 127.0 / fmax((double)amax, 1e-5);
  const double wmean = *wsum * (1.0 / 16777216.0);
  const double b_scale = 1.0 / fmax(wmean, 1e-5);
  const float dq = (float)(1.0 / (a_scale * b_scale));

#pragma unroll
  for (int m = 0; m < 4; m++) {
#pragma unroll
    for (int n = 0; n < 4; n++) {
      const int row = wm * 64 + m * 16 + (lane >> 4) * 4;
      const int col = wn * 64 + n * 16 + (lane & 15);
#pragma unroll
      for (int j = 0; j < 4; j++) {
        out[(size_t)(brow + row + j) * N_DIM + bcol + col] = acc[m][n][j] * dq;
      }
    }
  }
}

// ============================================================================
extern "C" void kernel_launch(void* const* d_in, const int* in_sizes, int n_in,
                              void* d_out, int out_size, void* d_ws, size_t ws_size,
                              hipStream_t stream) {
  const float* x      = (const float*)d_in[0];   // [1,2048,4096]
  const float* weight = (const float*)d_in[1];   // [4096,4096]
  const float* rms_w  = (const float*)d_in[2];   // [4096]
  float* out = (float*)d_out;

  uint8_t* ws = (uint8_t*)d_ws;
  unsigned* absmax_bits = (unsigned*)ws;                         // 4B @ 0
  double* wsum          = (double*)(ws + 8);                     // 8B @ 8
  float* invrms         = (float*)(ws + 64);                     // 8KB
  double* partials      = (double*)(ws + 64 + 2048 * 4);         // 16KB
  u16* Aq = (u16*)(ws + 32768);                                  // 16MB
  u16* Bt = (u16*)(ws + 32768 + (size_t)M_DIM * K_DIM * 2);      // 32MB

  hipMemsetAsync(absmax_bits, 0, 8, stream);  // re-init scalar each call (deterministic)
  rms_absmax_kernel<<<M_DIM, 256, 0, stream>>>(x, rms_w, invrms, absmax_bits);
  wsum_partial_kernel<<<2048, 256, 0, stream>>>(weight, partials);
  wsum_final_kernel<<<1, 256, 0, stream>>>(partials, wsum);
  aquant_kernel<<<M_DIM, 256, 0, stream>>>(x, rms_w, invrms, absmax_bits, Aq);
  wquant_kernel<<<dim3(N_DIM / 64, K_DIM / 64), 256, 0, stream>>>(weight, wsum, Bt);
  gemm_kernel<<<dim3(N_DIM / 128, M_DIM / 128), 256, 0, stream>>>(Aq, Bt, out, absmax_bits, wsum);
}

// Round 2
// 119.174 us; speedup vs baseline: 1.3378x; 1.3378x over previous
//
#include <hip/hip_runtime.h>
#include <hip/hip_bf16.h>
#include <cstdint>

#define M_DIM 2048
#define K_DIM 4096
#define N_DIM 4096

typedef __attribute__((ext_vector_type(4))) int i32x4;

// ---- async global->LDS, 16B per lane (dest = wave-uniform base + lane*16) ----
__device__ __forceinline__ void gload_lds16(const void* g, void* l) {
  __builtin_amdgcn_global_load_lds(
      (__attribute__((address_space(1))) void*)(g),
      (__attribute__((address_space(3))) void*)(l), 16, 0, 0);
}

// ============================================================================
// K1: per-row RMS sum-of-squares (double), per-row inv_rms, global absmax of
//     normalized activations (atomicMax on float bits; all values >= 0).
// ============================================================================
__global__ void rms_absmax_kernel(const float* __restrict__ x,
                                  const float* __restrict__ rw,
                                  float* __restrict__ invrms,
                                  unsigned* __restrict__ absmax_bits) {
  const int row = blockIdx.x;
  const int tid = threadIdx.x;
  const float4* xr = (const float4*)(x + (size_t)row * K_DIM);
  const float4* wr = (const float4*)rw;

  float4 xv[4];
  double ss = 0.0;
#pragma unroll
  for (int i = 0; i < 4; i++) {
    xv[i] = xr[i * 256 + tid];
    ss += (double)xv[i].x * xv[i].x + (double)xv[i].y * xv[i].y +
          (double)xv[i].z * xv[i].z + (double)xv[i].w * xv[i].w;
  }
  __shared__ double red[4];
  __shared__ float redf[4];
  __shared__ float sInv;
  for (int off = 32; off; off >>= 1) ss += __shfl_down(ss, off);
  if ((tid & 63) == 0) red[tid >> 6] = ss;
  __syncthreads();
  if (tid == 0) {
    double t = red[0] + red[1] + red[2] + red[3];
    double inv = 1.0 / sqrt(t * (1.0 / (double)K_DIM) + 1e-6);
    sInv = (float)inv;
  }
  __syncthreads();
  const float inv = sInv;
  if (tid == 0) invrms[row] = inv;

  float amax = 0.f;
#pragma unroll
  for (int i = 0; i < 4; i++) {
    float4 wv = wr[i * 256 + tid];
    amax = fmaxf(amax, fabsf((xv[i].x * inv) * wv.x));
    amax = fmaxf(amax, fabsf((xv[i].y * inv) * wv.y));
    amax = fmaxf(amax, fabsf((xv[i].z * inv) * wv.z));
    amax = fmaxf(amax, fabsf((xv[i].w * inv) * wv.w));
  }
  for (int off = 32; off; off >>= 1) amax = fmaxf(amax, __shfl_down(amax, off));
  if ((tid & 63) == 0) redf[tid >> 6] = amax;
  __syncthreads();
  if (tid == 0) {
    float m = fmaxf(fmaxf(redf[0], redf[1]), fmaxf(redf[2], redf[3]));
    atomicMax(absmax_bits, __float_as_uint(m));  // floats >= 0: bit-order == value-order
  }
}

// ============================================================================
// K2a/K2b: deterministic two-stage sum of |W| (f32 4-chains into double accum)
// ============================================================================
__global__ void wsum_partial_kernel(const float* __restrict__ w,
                                    double* __restrict__ partials) {
  const int tid = threadIdx.x;
  const int bid = blockIdx.x;
  const float4* w4 = (const float4*)w;
  const size_t base = (size_t)bid * 2048;
  double s = 0.0;
#pragma unroll
  for (int i = 0; i < 8; i++) {
    float4 v = w4[base + i * 256 + tid];
    s += (double)((fabsf(v.x) + fabsf(v.y)) + (fabsf(v.z) + fabsf(v.w)));
  }
  for (int off = 32; off; off >>= 1) s += __shfl_down(s, off);
  __shared__ double red[4];
  if ((tid & 63) == 0) red[tid >> 6] = s;
  __syncthreads();
  if (tid == 0) partials[bid] = red[0] + red[1] + red[2] + red[3];
}

__global__ void wsum_final_kernel(const double* __restrict__ partials,
                                  double* __restrict__ wsum) {
  const int tid = threadIdx.x;
  double s = 0.0;
#pragma unroll
  for (int i = 0; i < 8; i++) s += partials[i * 256 + tid];
  for (int off = 32; off; off >>= 1) s += __shfl_down(s, off);
  __shared__ double red[4];
  if ((tid & 63) == 0) red[tid >> 6] = s;
  __syncthreads();
  if (tid == 0) *wsum = red[0] + red[1] + red[2] + red[3];
}

// ============================================================================
// K3: quantize activations to int8: clip(rintf(xn * a_scale), -128, 127)
//     f32 math matches the reference's own f32 expression order.
// ============================================================================
__global__ void aquant_kernel(const float* __restrict__ x,
                              const float* __restrict__ rw,
                              const float* __restrict__ invrms,
                              const unsigned* __restrict__ absmax_bits,
                              char* __restrict__ Aq) {
  const int row = blockIdx.x;
  const int tid = threadIdx.x;
  const float inv = invrms[row];
  const float as = 127.0f / fmaxf(__uint_as_float(*absmax_bits), 1e-5f);
  const float4* xr = (const float4*)(x + (size_t)row * K_DIM);
  const float4* wr = (const float4*)rw;
  union { char c[16]; int4 v; } o;
#pragma unroll
  for (int i = 0; i < 4; i++) {
    float4 xv = xr[tid * 4 + i];
    float4 wv = wr[tid * 4 + i];
    float t0 = (xv.x * inv) * wv.x;
    float t1 = (xv.y * inv) * wv.y;
    float t2 = (xv.z * inv) * wv.z;
    float t3 = (xv.w * inv) * wv.w;
    o.c[i * 4 + 0] = (char)(int)fminf(fmaxf(rintf(t0 * as), -128.f), 127.f);
    o.c[i * 4 + 1] = (char)(int)fminf(fmaxf(rintf(t1 * as), -128.f), 127.f);
    o.c[i * 4 + 2] = (char)(int)fminf(fmaxf(rintf(t2 * as), -128.f), 127.f);
    o.c[i * 4 + 3] = (char)(int)fminf(fmaxf(rintf(t3 * as), -128.f), 127.f);
  }
  *(int4*)(Aq + (size_t)row * K_DIM + tid * 16) = o.v;
}

// ============================================================================
// K4: ternary-quantize weight to int8 AND transpose: Bt[n][k]
//     64x64 tile through padded LDS; 16B packed writes.
// ============================================================================
__global__ void wquant_kernel(const float* __restrict__ w,
                              const double* __restrict__ wsum,
                              char* __restrict__ Bt) {
  __shared__ float lds[64][68];  // [n][k], row stride 272B (16B-aligned)
  const int tid = threadIdx.x;
  const int n0 = blockIdx.x * 64;
  const int k0 = blockIdx.y * 64;
  const float mean_f = (float)(*wsum * (1.0 / 16777216.0));
  const float bs = 1.0f / fmaxf(mean_f, 1e-5f);
#pragma unroll
  for (int i = 0; i < 4; i++) {
    const int id = i * 256 + tid;     // 0..1023
    const int r = id >> 4;            // k-row in tile
    const int c4 = (id & 15) * 4;     // n-col in tile
    float4 v = *(const float4*)(w + (size_t)(k0 + r) * N_DIM + n0 + c4);
    lds[c4 + 0][r] = fminf(fmaxf(rintf(v.x * bs), -1.f), 1.f);
    lds[c4 + 1][r] = fminf(fmaxf(rintf(v.y * bs), -1.f), 1.f);
    lds[c4 + 2][r] = fminf(fmaxf(rintf(v.z * bs), -1.f), 1.f);
    lds[c4 + 3][r] = fminf(fmaxf(rintf(v.w * bs), -1.f), 1.f);
  }
  __syncthreads();
  const int rn = tid >> 2;            // n-row of Bt tile (0..63)
  const int kg = (tid & 3) * 16;      // k-col group
  union { char c[16]; int4 v; } o;
#pragma unroll
  for (int j = 0; j < 16; j++) o.c[j] = (char)(int)lds[rn][kg + j];
  *(int4*)(Bt + (size_t)(n0 + rn) * K_DIM + k0 + kg) = o.v;
}

// ============================================================================
// K5: int8 GEMM, m97 structure: 128x128 tile, BK=64, 4 waves (2x2) of 64x64,
//     global_load_lds width=16, mfma_i32_16x16x64_i8, exact i32 accumulate.
//     Fragment layout: lane l -> row (l&15), k = (l>>4)*16 + j (16 consec i8).
// ============================================================================
__global__ void gemm_kernel(const char* __restrict__ Aq, const char* __restrict__ Bt,
                            float* __restrict__ out,
                            const unsigned* __restrict__ absmax_bits,
                            const double* __restrict__ wsum) {
  __shared__ char As[128 * 64];
  __shared__ char Bs[128 * 64];
  const int tid = threadIdx.x;
  const int lane = tid & 63;
  const int wave = tid >> 6;
  const int wm = wave >> 1, wn = wave & 1;
  const int brow = blockIdx.y * 128;
  const int bcol = blockIdx.x * 128;

  i32x4 acc[4][4];
#pragma unroll
  for (int m = 0; m < 4; m++)
#pragma unroll
    for (int n = 0; n < 4; n++) acc[m][n] = {0, 0, 0, 0};

  const int srow = lane >> 2;         // 0..15 (row within 16-row chunk)
  const int scol = (lane & 3) * 16;   // 0,16,32,48 (byte col)

  for (int k0 = 0; k0 < K_DIM; k0 += 64) {
    // stage A,B tiles: 8 chunks each of (16 rows x 64B) = 1KB per gload op
#pragma unroll
    for (int i = 0; i < 2; i++) {
      const int chunk = i * 4 + wave;  // wave-uniform
      gload_lds16(Aq + (size_t)(brow + chunk * 16 + srow) * K_DIM + k0 + scol,
                  As + chunk * 1024);
      gload_lds16(Bt + (size_t)(bcol + chunk * 16 + srow) * K_DIM + k0 + scol,
                  Bs + chunk * 1024);
    }
    __syncthreads();  // drains vmcnt(0): loads landed

    i32x4 a[4], b[4];
#pragma unroll
    for (int m = 0; m < 4; m++) {
      const int ar = wm * 64 + m * 16 + (lane & 15);
      a[m] = *(const i32x4*)(As + ar * 64 + (lane >> 4) * 16);
    }
#pragma unroll
    for (int n = 0; n < 4; n++) {
      const int br = wn * 64 + n * 16 + (lane & 15);
      b[n] = *(const i32x4*)(Bs + br * 64 + (lane >> 4) * 16);
    }
#pragma unroll
    for (int m = 0; m < 4; m++)
#pragma unroll
      for (int n = 0; n < 4; n++)
        acc[m][n] = __builtin_amdgcn_mfma_i32_16x16x64_i8(a[m], b[n], acc[m][n], 0, 0, 0);
    __syncthreads();  // compute done before next stage overwrites
  }

  const float amax = __uint_as_float(*absmax_bits);
  const float mean_f = (float)(*wsum * (1.0 / 16777216.0));
  const float as = 127.0f / fmaxf(amax, 1e-5f);
  const float bs = 1.0f / fmaxf(mean_f, 1e-5f);
  const float dq = 1.0f / (as * bs);

#pragma unroll
  for (int m = 0; m < 4; m++) {
#pragma unroll
    for (int n = 0; n < 4; n++) {
      const int row = wm * 64 + m * 16 + (lane >> 4) * 4;
      const int col = wn * 64 + n * 16 + (lane & 15);
#pragma unroll
      for (int j = 0; j < 4; j++) {
        out[(size_t)(brow + row + j) * N_DIM + bcol + col] = (float)acc[m][n][j] * dq;
      }
    }
  }
}

// ============================================================================
extern "C" void kernel_launch(void* const* d_in, const int* in_sizes, int n_in,
                              void* d_out, int out_size, void* d_ws, size_t ws_size,
                              hipStream_t stream) {
  const float* x      = (const float*)d_in[0];   // [1,2048,4096]
  const float* weight = (const float*)d_in[1];   // [4096,4096]
  const float* rms_w  = (const float*)d_in[2];   // [4096]
  float* out = (float*)d_out;

  uint8_t* ws = (uint8_t*)d_ws;
  unsigned* absmax_bits = (unsigned*)ws;                         // 4B @ 0
  double* wsum          = (double*)(ws + 8);                     // 8B @ 8
  float* invrms         = (float*)(ws + 64);                     // 8KB
  double* partials      = (double*)(ws + 64 + 2048 * 4);         // 16KB
  char* Aq = (char*)(ws + 32768);                                // 8MB
  char* Bt = (char*)(ws + 32768 + (size_t)M_DIM * K_DIM);        // 16MB

  hipMemsetAsync(absmax_bits, 0, 8, stream);  // re-init scalar each call (deterministic)
  rms_absmax_kernel<<<M_DIM, 256, 0, stream>>>(x, rms_w, invrms, absmax_bits);
  wsum_partial_kernel<<<2048, 256, 0, stream>>>(weight, partials);
  wsum_final_kernel<<<1, 256, 0, stream>>>(partials, wsum);
  aquant_kernel<<<M_DIM, 256, 0, stream>>>(x, rms_w, invrms, absmax_bits, Aq);
  wquant_kernel<<<dim3(N_DIM / 64, K_DIM / 64), 256, 0, stream>>>(weight, wsum, Bt);
  gemm_kernel<<<dim3(N_DIM / 128, M_DIM / 128), 256, 0, stream>>>(Aq, Bt, out, absmax_bits, wsum);
}

// Round 3
// 96.863 us; speedup vs baseline: 1.6459x; 1.2303x over previous
//
#include <hip/hip_runtime.h>
#include <cstdint>

#define M_DIM 2048
#define K_DIM 4096
#define N_DIM 4096

#define BM 256
#define BN 128
#define BK 128                       // i8 elements = bytes per K-tile row
#define KT (K_DIM / BK)              // 32 K-tiles
#define A_TILE_BYTES (BM * BK)       // 32 KiB
#define B_TILE_BYTES (BN * BK)       // 16 KiB
#define TILE_BYTES (A_TILE_BYTES + B_TILE_BYTES)  // 48 KiB
#define NBUF 3
#define LDS_BYTES (NBUF * TILE_BYTES)             // 144 KiB

typedef __attribute__((ext_vector_type(4))) int i32x4;

__device__ __forceinline__ void gload_lds16(const void* g, void* l) {
  __builtin_amdgcn_global_load_lds(
      (__attribute__((address_space(1))) void*)(g),
      (__attribute__((address_space(3))) void*)(l), 16, 0, 0);
}

// ============================================================================
// P1: fused reducers. blocks [0,2048): per-row RMS + global absmax of xn.
//     blocks [2048,4096): |W| partial sums (deterministic double tree).
// ============================================================================
__global__ void fused_reduce_kernel(const float* __restrict__ x,
                                    const float* __restrict__ rw,
                                    const float* __restrict__ w,
                                    float* __restrict__ invrms,
                                    unsigned* __restrict__ absmax_bits,
                                    double* __restrict__ partials) {
  const int tid = threadIdx.x;
  __shared__ double red[4];
  __shared__ float redf[4];
  __shared__ float sInv;

  if (blockIdx.x < 2048) {
    const int row = blockIdx.x;
    const float4* xr = (const float4*)(x + (size_t)row * K_DIM);
    const float4* wr = (const float4*)rw;
    float4 xv[4];
    double ss = 0.0;
#pragma unroll
    for (int i = 0; i < 4; i++) {
      xv[i] = xr[i * 256 + tid];
      ss += (double)xv[i].x * xv[i].x + (double)xv[i].y * xv[i].y +
            (double)xv[i].z * xv[i].z + (double)xv[i].w * xv[i].w;
    }
    for (int off = 32; off; off >>= 1) ss += __shfl_down(ss, off);
    if ((tid & 63) == 0) red[tid >> 6] = ss;
    __syncthreads();
    if (tid == 0) {
      double t = red[0] + red[1] + red[2] + red[3];
      sInv = (float)(1.0 / sqrt(t * (1.0 / (double)K_DIM) + 1e-6));
    }
    __syncthreads();
    const float inv = sInv;
    if (tid == 0) invrms[row] = inv;

    float amax = 0.f;
#pragma unroll
    for (int i = 0; i < 4; i++) {
      float4 wv = wr[i * 256 + tid];
      amax = fmaxf(amax, fabsf((xv[i].x * inv) * wv.x));
      amax = fmaxf(amax, fabsf((xv[i].y * inv) * wv.y));
      amax = fmaxf(amax, fabsf((xv[i].z * inv) * wv.z));
      amax = fmaxf(amax, fabsf((xv[i].w * inv) * wv.w));
    }
    for (int off = 32; off; off >>= 1) amax = fmaxf(amax, __shfl_down(amax, off));
    if ((tid & 63) == 0) redf[tid >> 6] = amax;
    __syncthreads();
    if (tid == 0) {
      float m = fmaxf(fmaxf(redf[0], redf[1]), fmaxf(redf[2], redf[3]));
      atomicMax(absmax_bits, __float_as_uint(m));  // >=0 floats: bit order == value order
    }
  } else {
    const int bid = blockIdx.x - 2048;
    const float4* w4 = (const float4*)w;
    const size_t base = (size_t)bid * 2048;
    double s = 0.0;
#pragma unroll
    for (int i = 0; i < 8; i++) {
      float4 v = w4[base + i * 256 + tid];
      s += (double)((fabsf(v.x) + fabsf(v.y)) + (fabsf(v.z) + fabsf(v.w)));
    }
    for (int off = 32; off; off >>= 1) s += __shfl_down(s, off);
    if ((tid & 63) == 0) red[tid >> 6] = s;
    __syncthreads();
    if (tid == 0) partials[bid] = red[0] + red[1] + red[2] + red[3];
  }
}

__global__ void wsum_final_kernel(const double* __restrict__ partials,
                                  double* __restrict__ wsum) {
  const int tid = threadIdx.x;
  double s = 0.0;
#pragma unroll
  for (int i = 0; i < 8; i++) s += partials[i * 256 + tid];
  for (int off = 32; off; off >>= 1) s += __shfl_down(s, off);
  __shared__ double red[4];
  if ((tid & 63) == 0) red[tid >> 6] = s;
  __syncthreads();
  if (tid == 0) *wsum = red[0] + red[1] + red[2] + red[3];
}

// ============================================================================
// P2: fused quantizers. blocks [0,2048): A_q rows (int8). blocks [2048,6144):
//     64x64 ternary weight tiles, transposed to Bt[n][k] via padded LDS.
// ============================================================================
__global__ void fused_quant_kernel(const float* __restrict__ x,
                                   const float* __restrict__ rw,
                                   const float* __restrict__ invrms,
                                   const unsigned* __restrict__ absmax_bits,
                                   const float* __restrict__ w,
                                   const double* __restrict__ wsum,
                                   char* __restrict__ Aq,
                                   char* __restrict__ Bt) {
  const int tid = threadIdx.x;
  if (blockIdx.x < 2048) {
    const int row = blockIdx.x;
    const float inv = invrms[row];
    const float as = 127.0f / fmaxf(__uint_as_float(*absmax_bits), 1e-5f);
    const float4* xr = (const float4*)(x + (size_t)row * K_DIM);
    const float4* wr = (const float4*)rw;
    union { char c[16]; int4 v; } o;
#pragma unroll
    for (int i = 0; i < 4; i++) {
      float4 xv = xr[tid * 4 + i];
      float4 wv = wr[tid * 4 + i];
      float t0 = (xv.x * inv) * wv.x;
      float t1 = (xv.y * inv) * wv.y;
      float t2 = (xv.z * inv) * wv.z;
      float t3 = (xv.w * inv) * wv.w;
      o.c[i * 4 + 0] = (char)(int)fminf(fmaxf(rintf(t0 * as), -128.f), 127.f);
      o.c[i * 4 + 1] = (char)(int)fminf(fmaxf(rintf(t1 * as), -128.f), 127.f);
      o.c[i * 4 + 2] = (char)(int)fminf(fmaxf(rintf(t2 * as), -128.f), 127.f);
      o.c[i * 4 + 3] = (char)(int)fminf(fmaxf(rintf(t3 * as), -128.f), 127.f);
    }
    *(int4*)(Aq + (size_t)row * K_DIM + tid * 16) = o.v;
  } else {
    __shared__ float lds[64][68];
    const int tile = blockIdx.x - 2048;
    const int n0 = (tile & 63) * 64;
    const int k0 = (tile >> 6) * 64;
    const float mean_f = (float)(*wsum * (1.0 / 16777216.0));
    const float bs = 1.0f / fmaxf(mean_f, 1e-5f);
#pragma unroll
    for (int i = 0; i < 4; i++) {
      const int id = i * 256 + tid;
      const int r = id >> 4;
      const int c4 = (id & 15) * 4;
      float4 v = *(const float4*)(w + (size_t)(k0 + r) * N_DIM + n0 + c4);
      lds[c4 + 0][r] = fminf(fmaxf(rintf(v.x * bs), -1.f), 1.f);
      lds[c4 + 1][r] = fminf(fmaxf(rintf(v.y * bs), -1.f), 1.f);
      lds[c4 + 2][r] = fminf(fmaxf(rintf(v.z * bs), -1.f), 1.f);
      lds[c4 + 3][r] = fminf(fmaxf(rintf(v.w * bs), -1.f), 1.f);
    }
    __syncthreads();
    const int rn = tid >> 2;
    const int kg = (tid & 3) * 16;
    union { char c[16]; int4 v; } o;
#pragma unroll
    for (int j = 0; j < 16; j++) o.c[j] = (char)(int)lds[rn][kg + j];
    *(int4*)(Bt + (size_t)(n0 + rn) * K_DIM + k0 + kg) = o.v;
  }
}

// ============================================================================
// K5: i8 GEMM, counted-vmcnt pipeline (T3+T4), triple-buffered LDS staged 2
//     K-tiles ahead, ONE barrier + ONE s_waitcnt vmcnt(6) per K-tile (never 0
//     in steady state), T2 XOR-swizzle via inverse-swizzled global source +
//     swizzled ds_read (rule #21), T5 setprio around MFMA clusters.
//     BM=256 x BN=128 x BK=128, 512 thr / 8 waves (4M x 2N), wave tile 64x64.
// Hazards: (a) tile-t data landed for ALL waves: every wave's own vmcnt(6)
//     covers its 6 tile-t loads, then the barrier joins; (b) staging t+2 vs
//     reads of t-1 (same buffer): all t-1 ds_reads complete before the wave
//     reaches barrier t (MFMA consumed them), staging issues after barrier t;
//     barrier bounds wave skew to < 1 iteration.
// ============================================================================
__global__ void __launch_bounds__(512, 2)
gemm_kernel(const char* __restrict__ Aq, const char* __restrict__ Bt,
            float* __restrict__ out,
            const unsigned* __restrict__ absmax_bits,
            const double* __restrict__ wsum) {
  extern __shared__ char lds[];
  const int tid = threadIdx.x;
  const int lane = tid & 63;
  const int wave = tid >> 6;      // 0..7
  const int wm = wave >> 1;       // 0..3 -> 64-row band
  const int wn = wave & 1;        // 0..1 -> 64-col band
  const int brow = blockIdx.y * BM;
  const int bcol = blockIdx.x * BN;

  i32x4 acc[4][4];
#pragma unroll
  for (int m = 0; m < 4; m++)
#pragma unroll
    for (int n = 0; n < 4; n++) acc[m][n] = {0, 0, 0, 0};

  // ---- staging geometry (per lane, sweep-independent) ----
  // sweep s covers 64 rows (8KB): row = s*64 + wave*8 + (lane>>3), col16 = lane&7.
  // row&7 == lane>>3, so swizzled source col16 = (lane&7) ^ (lane>>3).
  const int sRow8 = lane >> 3;                    // 0..7
  const int srcColB = ((lane & 7) ^ sRow8) * 16;  // inverse-swizzled source byte col

#define STAGE_A(kt, bi, s)                                                        \
  gload_lds16(Aq + (size_t)(brow + (s)*64 + wave * 8 + sRow8) * K_DIM +           \
                  (kt)*BK + srcColB,                                              \
              lds + (bi)*TILE_BYTES + (s)*8192 + wave * 1024 + lane * 16)
#define STAGE_B(kt, bi, s)                                                        \
  gload_lds16(Bt + (size_t)(bcol + (s)*64 + wave * 8 + sRow8) * K_DIM +           \
                  (kt)*BK + srcColB,                                              \
              lds + (bi)*TILE_BYTES + A_TILE_BYTES + (s)*8192 + wave * 1024 +     \
                  lane * 16)

  // ---- prologue: stage tiles 0 and 1 (6 sweeps each; 12 outstanding/wave) ----
  STAGE_A(0, 0, 0); STAGE_A(0, 0, 1); STAGE_A(0, 0, 2); STAGE_A(0, 0, 3);
  STAGE_B(0, 0, 0); STAGE_B(0, 0, 1);
  STAGE_A(1, 1, 0); STAGE_A(1, 1, 1); STAGE_A(1, 1, 2); STAGE_A(1, 1, 3);
  STAGE_B(1, 1, 0); STAGE_B(1, 1, 1);

  const int frow = lane & 15;
  int bi = 0;
  for (int t = 0; t < KT; ++t) {
    // tile t landed when <=6 newest (tile t+1's) loads remain in flight
    if (t < KT - 1) {
      asm volatile("s_waitcnt vmcnt(6)" ::: "memory");
    } else {
      asm volatile("s_waitcnt vmcnt(0)" ::: "memory");
    }
    __builtin_amdgcn_s_barrier();

    const int si = (bi + 2 >= NBUF) ? bi + 2 - NBUF : bi + 2;
    const bool doStage = (t + 2) < KT;
    const char* bufA = lds + bi * TILE_BYTES;
    const char* bufB = bufA + A_TILE_BYTES;

    if (doStage) {
      STAGE_A(t + 2, si, 0); STAGE_A(t + 2, si, 1); STAGE_A(t + 2, si, 2);
    }
    // ---- kk = 0 ----
    {
      const int sc = ((0 * 4 + (lane >> 4)) ^ (lane & 7)) * 16;  // swizzled col
      i32x4 a[4], b[4];
#pragma unroll
      for (int m = 0; m < 4; m++)
        a[m] = *(const i32x4*)(bufA + (wm * 64 + m * 16 + frow) * BK + sc);
#pragma unroll
      for (int n = 0; n < 4; n++)
        b[n] = *(const i32x4*)(bufB + (wn * 64 + n * 16 + frow) * BK + sc);
      __builtin_amdgcn_s_setprio(1);
#pragma unroll
      for (int m = 0; m < 4; m++)
#pragma unroll
        for (int n = 0; n < 4; n++)
          acc[m][n] = __builtin_amdgcn_mfma_i32_16x16x64_i8(a[m], b[n], acc[m][n], 0, 0, 0);
      __builtin_amdgcn_s_setprio(0);
    }
    if (doStage) {
      STAGE_A(t + 2, si, 3); STAGE_B(t + 2, si, 0); STAGE_B(t + 2, si, 1);
    }
    // ---- kk = 1 ----
    {
      const int sc = ((1 * 4 + (lane >> 4)) ^ (lane & 7)) * 16;
      i32x4 a[4], b[4];
#pragma unroll
      for (int m = 0; m < 4; m++)
        a[m] = *(const i32x4*)(bufA + (wm * 64 + m * 16 + frow) * BK + sc);
#pragma unroll
      for (int n = 0; n < 4; n++)
        b[n] = *(const i32x4*)(bufB + (wn * 64 + n * 16 + frow) * BK + sc);
      __builtin_amdgcn_s_setprio(1);
#pragma unroll
      for (int m = 0; m < 4; m++)
#pragma unroll
        for (int n = 0; n < 4; n++)
          acc[m][n] = __builtin_amdgcn_mfma_i32_16x16x64_i8(a[m], b[n], acc[m][n], 0, 0, 0);
      __builtin_amdgcn_s_setprio(0);
    }
    bi = (bi + 1 >= NBUF) ? 0 : bi + 1;
  }
#undef STAGE_A
#undef STAGE_B

  const float amax = __uint_as_float(*absmax_bits);
  const float mean_f = (float)(*wsum * (1.0 / 16777216.0));
  const float as = 127.0f / fmaxf(amax, 1e-5f);
  const float bsc = 1.0f / fmaxf(mean_f, 1e-5f);
  const float dq = 1.0f / (as * bsc);

#pragma unroll
  for (int m = 0; m < 4; m++) {
#pragma unroll
    for (int n = 0; n < 4; n++) {
      const int row = wm * 64 + m * 16 + (lane >> 4) * 4;
      const int col = wn * 64 + n * 16 + (lane & 15);
#pragma unroll
      for (int j = 0; j < 4; j++) {
        out[(size_t)(brow + row + j) * N_DIM + bcol + col] = (float)acc[m][n][j] * dq;
      }
    }
  }
}

// ============================================================================
extern "C" void kernel_launch(void* const* d_in, const int* in_sizes, int n_in,
                              void* d_out, int out_size, void* d_ws, size_t ws_size,
                              hipStream_t stream) {
  const float* x      = (const float*)d_in[0];   // [1,2048,4096]
  const float* weight = (const float*)d_in[1];   // [4096,4096]
  const float* rms_w  = (const float*)d_in[2];   // [4096]
  float* out = (float*)d_out;

  uint8_t* ws = (uint8_t*)d_ws;
  unsigned* absmax_bits = (unsigned*)ws;                         // 4B
  double* wsum          = (double*)(ws + 8);                     // 8B
  float* invrms         = (float*)(ws + 64);                     // 8KB
  double* partials      = (double*)(ws + 64 + 2048 * 4);         // 16KB
  char* Aq = (char*)(ws + 32768);                                // 8MB
  char* Bt = (char*)(ws + 32768 + (size_t)M_DIM * K_DIM);        // 16MB

  static int lds_attr_set = 0;  // attribute is persistent per-process; set once
  if (!lds_attr_set) {
    (void)hipFuncSetAttribute((const void*)gemm_kernel,
                              hipFuncAttributeMaxDynamicSharedMemorySize, LDS_BYTES);
    lds_attr_set = 1;
  }

  hipMemsetAsync(absmax_bits, 0, 8, stream);
  fused_reduce_kernel<<<4096, 256, 0, stream>>>(x, rms_w, weight, invrms, absmax_bits, partials);
  wsum_final_kernel<<<1, 256, 0, stream>>>(partials, wsum);
  fused_quant_kernel<<<6144, 256, 0, stream>>>(x, rms_w, invrms, absmax_bits, weight, wsum, Aq, Bt);
  gemm_kernel<<<dim3(N_DIM / BN, M_DIM / BM), 512, LDS_BYTES, stream>>>(Aq, Bt, out, absmax_bits, wsum);
}

// Round 4
// 74.343 us; speedup vs baseline: 2.1445x; 1.3029x over previous
//
#include <hip/hip_runtime.h>
#include <cstdint>

#define M_DIM 2048
#define K_DIM 4096
#define N_DIM 4096

#define BM 256
#define BN 128
#define BK 128                       // i8 elements = bytes per K-tile row
#define KT (K_DIM / BK)              // 32 K-tiles
#define A_TILE_BYTES (BM * BK)       // 32 KiB
#define B_TILE_BYTES (BN * BK)       // 16 KiB
#define TILE_BYTES (A_TILE_BYTES + B_TILE_BYTES)  // 48 KiB
#define NBUF 3
#define LDS_BYTES (NBUF * TILE_BYTES)             // 144 KiB

typedef __attribute__((ext_vector_type(4))) int i32x4;

__device__ __forceinline__ void gload_lds16(const void* g, void* l) {
  __builtin_amdgcn_global_load_lds(
      (__attribute__((address_space(1))) void*)(g),
      (__attribute__((address_space(3))) void*)(l), 16, 0, 0);
}

// ============================================================================
// K1: fused reducers — NO global atomics.
//     blocks [0,2048):   per-row RMS -> invrms[row]; per-row absmax of xn
//                        -> rowmax[row] (exclusive slot, plain store).
//     blocks [2048,4096): |W| partial sums -> partials[bid] (double tree).
// ============================================================================
__global__ void fused_reduce_kernel(const float* __restrict__ x,
                                    const float* __restrict__ rw,
                                    const float* __restrict__ w,
                                    float* __restrict__ invrms,
                                    float* __restrict__ rowmax,
                                    double* __restrict__ partials) {
  const int tid = threadIdx.x;
  __shared__ double red[4];
  __shared__ float redf[4];
  __shared__ float sInv;

  if (blockIdx.x < 2048) {
    const int row = blockIdx.x;
    const float4* xr = (const float4*)(x + (size_t)row * K_DIM);
    const float4* wr = (const float4*)rw;
    float4 xv[4];
    double ss = 0.0;
#pragma unroll
    for (int i = 0; i < 4; i++) {
      xv[i] = xr[i * 256 + tid];
      ss += (double)xv[i].x * xv[i].x + (double)xv[i].y * xv[i].y +
            (double)xv[i].z * xv[i].z + (double)xv[i].w * xv[i].w;
    }
    for (int off = 32; off; off >>= 1) ss += __shfl_down(ss, off);
    if ((tid & 63) == 0) red[tid >> 6] = ss;
    __syncthreads();
    if (tid == 0) {
      double t = red[0] + red[1] + red[2] + red[3];
      sInv = (float)(1.0 / sqrt(t * (1.0 / (double)K_DIM) + 1e-6));
    }
    __syncthreads();
    const float inv = sInv;
    if (tid == 0) invrms[row] = inv;

    float amax = 0.f;
#pragma unroll
    for (int i = 0; i < 4; i++) {
      float4 wv = wr[i * 256 + tid];
      amax = fmaxf(amax, fabsf((xv[i].x * inv) * wv.x));
      amax = fmaxf(amax, fabsf((xv[i].y * inv) * wv.y));
      amax = fmaxf(amax, fabsf((xv[i].z * inv) * wv.z));
      amax = fmaxf(amax, fabsf((xv[i].w * inv) * wv.w));
    }
    for (int off = 32; off; off >>= 1) amax = fmaxf(amax, __shfl_down(amax, off));
    if ((tid & 63) == 0) redf[tid >> 6] = amax;
    __syncthreads();
    if (tid == 0)
      rowmax[row] = fmaxf(fmaxf(redf[0], redf[1]), fmaxf(redf[2], redf[3]));
  } else {
    const int bid = blockIdx.x - 2048;
    const float4* w4 = (const float4*)w;
    const size_t base = (size_t)bid * 2048;
    double s = 0.0;
#pragma unroll
    for (int i = 0; i < 8; i++) {
      float4 v = w4[base + i * 256 + tid];
      s += (double)((fabsf(v.x) + fabsf(v.y)) + (fabsf(v.z) + fabsf(v.w)));
    }
    for (int off = 32; off; off >>= 1) s += __shfl_down(s, off);
    if ((tid & 63) == 0) red[tid >> 6] = s;
    __syncthreads();
    if (tid == 0) partials[bid] = red[0] + red[1] + red[2] + red[3];
  }
}

// ============================================================================
// K2: single-block scale finalizer: amax = max(rowmax[0..2048)),
//     wsum = sum(partials[0..2048)), then scales = {a_scale, b_scale, dq}.
// ============================================================================
__global__ void scales_kernel(const float* __restrict__ rowmax,
                              const double* __restrict__ partials,
                              float* __restrict__ scales) {
  const int tid = threadIdx.x;
  float m = 0.f;
  double s = 0.0;
#pragma unroll
  for (int i = 0; i < 8; i++) {
    m = fmaxf(m, rowmax[i * 256 + tid]);
    s += partials[i * 256 + tid];
  }
  for (int off = 32; off; off >>= 1) {
    m = fmaxf(m, __shfl_down(m, off));
    s += __shfl_down(s, off);
  }
  __shared__ float redf[4];
  __shared__ double red[4];
  if ((tid & 63) == 0) { redf[tid >> 6] = m; red[tid >> 6] = s; }
  __syncthreads();
  if (tid == 0) {
    float amax = fmaxf(fmaxf(redf[0], redf[1]), fmaxf(redf[2], redf[3]));
    double wsum = red[0] + red[1] + red[2] + red[3];
    float as = 127.0f / fmaxf(amax, 1e-5f);
    float mean_f = (float)(wsum * (1.0 / 16777216.0));
    float bs = 1.0f / fmaxf(mean_f, 1e-5f);
    scales[0] = as;
    scales[1] = bs;
    scales[2] = 1.0f / (as * bs);
  }
}

// ============================================================================
// K3: fused quantizers. blocks [0,2048): A_q rows (int8). blocks [2048,6144):
//     64x64 ternary weight tiles, transposed to Bt[n][k] via padded LDS.
// ============================================================================
__global__ void fused_quant_kernel(const float* __restrict__ x,
                                   const float* __restrict__ rw,
                                   const float* __restrict__ invrms,
                                   const float* __restrict__ scales,
                                   const float* __restrict__ w,
                                   char* __restrict__ Aq,
                                   char* __restrict__ Bt) {
  const int tid = threadIdx.x;
  if (blockIdx.x < 2048) {
    const int row = blockIdx.x;
    const float inv = invrms[row];
    const float as = scales[0];
    const float4* xr = (const float4*)(x + (size_t)row * K_DIM);
    const float4* wr = (const float4*)rw;
    union { char c[16]; int4 v; } o;
#pragma unroll
    for (int i = 0; i < 4; i++) {
      float4 xv = xr[tid * 4 + i];
      float4 wv = wr[tid * 4 + i];
      float t0 = (xv.x * inv) * wv.x;
      float t1 = (xv.y * inv) * wv.y;
      float t2 = (xv.z * inv) * wv.z;
      float t3 = (xv.w * inv) * wv.w;
      o.c[i * 4 + 0] = (char)(int)fminf(fmaxf(rintf(t0 * as), -128.f), 127.f);
      o.c[i * 4 + 1] = (char)(int)fminf(fmaxf(rintf(t1 * as), -128.f), 127.f);
      o.c[i * 4 + 2] = (char)(int)fminf(fmaxf(rintf(t2 * as), -128.f), 127.f);
      o.c[i * 4 + 3] = (char)(int)fminf(fmaxf(rintf(t3 * as), -128.f), 127.f);
    }
    *(int4*)(Aq + (size_t)row * K_DIM + tid * 16) = o.v;
  } else {
    __shared__ float lds[64][68];
    const int tile = blockIdx.x - 2048;
    const int n0 = (tile & 63) * 64;
    const int k0 = (tile >> 6) * 64;
    const float bs = scales[1];
#pragma unroll
    for (int i = 0; i < 4; i++) {
      const int id = i * 256 + tid;
      const int r = id >> 4;
      const int c4 = (id & 15) * 4;
      float4 v = *(const float4*)(w + (size_t)(k0 + r) * N_DIM + n0 + c4);
      lds[c4 + 0][r] = fminf(fmaxf(rintf(v.x * bs), -1.f), 1.f);
      lds[c4 + 1][r] = fminf(fmaxf(rintf(v.y * bs), -1.f), 1.f);
      lds[c4 + 2][r] = fminf(fmaxf(rintf(v.z * bs), -1.f), 1.f);
      lds[c4 + 3][r] = fminf(fmaxf(rintf(v.w * bs), -1.f), 1.f);
    }
    __syncthreads();
    const int rn = tid >> 2;
    const int kg = (tid & 3) * 16;
    union { char c[16]; int4 v; } o;
#pragma unroll
    for (int j = 0; j < 16; j++) o.c[j] = (char)(int)lds[rn][kg + j];
    *(int4*)(Bt + (size_t)(n0 + rn) * K_DIM + k0 + kg) = o.v;
  }
}

// ============================================================================
// K4: i8 GEMM, counted-vmcnt pipeline (T3+T4), triple-buffered LDS staged 2
//     K-tiles ahead, ONE barrier + ONE s_waitcnt vmcnt(6) per K-tile (never 0
//     in steady state), T2 XOR-swizzle via inverse-swizzled global source +
//     swizzled ds_read, T5 setprio around MFMA clusters.
//     BM=256 x BN=128 x BK=128, 512 thr / 8 waves (4M x 2N), wave tile 64x64.
// ============================================================================
__global__ void __launch_bounds__(512, 2)
gemm_kernel(const char* __restrict__ Aq, const char* __restrict__ Bt,
            float* __restrict__ out, const float* __restrict__ scales) {
  extern __shared__ char lds[];
  const int tid = threadIdx.x;
  const int lane = tid & 63;
  const int wave = tid >> 6;      // 0..7
  const int wm = wave >> 1;       // 0..3 -> 64-row band
  const int wn = wave & 1;        // 0..1 -> 64-col band
  const int brow = blockIdx.y * BM;
  const int bcol = blockIdx.x * BN;

  i32x4 acc[4][4];
#pragma unroll
  for (int m = 0; m < 4; m++)
#pragma unroll
    for (int n = 0; n < 4; n++) acc[m][n] = {0, 0, 0, 0};

  // sweep s covers 64 rows (8KB): row = s*64 + wave*8 + (lane>>3), col16 = lane&7.
  // row&7 == lane>>3, so swizzled source col16 = (lane&7) ^ (lane>>3).
  const int sRow8 = lane >> 3;                    // 0..7
  const int srcColB = ((lane & 7) ^ sRow8) * 16;  // inverse-swizzled source byte col

#define STAGE_A(kt, bi, s)                                                        \
  gload_lds16(Aq + (size_t)(brow + (s)*64 + wave * 8 + sRow8) * K_DIM +           \
                  (kt)*BK + srcColB,                                              \
              lds + (bi)*TILE_BYTES + (s)*8192 + wave * 1024 + lane * 16)
#define STAGE_B(kt, bi, s)                                                        \
  gload_lds16(Bt + (size_t)(bcol + (s)*64 + wave * 8 + sRow8) * K_DIM +           \
                  (kt)*BK + srcColB,                                              \
              lds + (bi)*TILE_BYTES + A_TILE_BYTES + (s)*8192 + wave * 1024 +     \
                  lane * 16)

  // prologue: stage tiles 0 and 1 (6 sweeps each; 12 outstanding per wave)
  STAGE_A(0, 0, 0); STAGE_A(0, 0, 1); STAGE_A(0, 0, 2); STAGE_A(0, 0, 3);
  STAGE_B(0, 0, 0); STAGE_B(0, 0, 1);
  STAGE_A(1, 1, 0); STAGE_A(1, 1, 1); STAGE_A(1, 1, 2); STAGE_A(1, 1, 3);
  STAGE_B(1, 1, 0); STAGE_B(1, 1, 1);

  const int frow = lane & 15;
  int bi = 0;
  for (int t = 0; t < KT; ++t) {
    if (t < KT - 1) {
      asm volatile("s_waitcnt vmcnt(6)" ::: "memory");
    } else {
      asm volatile("s_waitcnt vmcnt(0)" ::: "memory");
    }
    __builtin_amdgcn_s_barrier();

    const int si = (bi + 2 >= NBUF) ? bi + 2 - NBUF : bi + 2;
    const bool doStage = (t + 2) < KT;
    const char* bufA = lds + bi * TILE_BYTES;
    const char* bufB = bufA + A_TILE_BYTES;

    if (doStage) {
      STAGE_A(t + 2, si, 0); STAGE_A(t + 2, si, 1); STAGE_A(t + 2, si, 2);
    }
    // ---- kk = 0 ----
    {
      const int sc = ((0 * 4 + (lane >> 4)) ^ (lane & 7)) * 16;  // swizzled col
      i32x4 a[4], b[4];
#pragma unroll
      for (int m = 0; m < 4; m++)
        a[m] = *(const i32x4*)(bufA + (wm * 64 + m * 16 + frow) * BK + sc);
#pragma unroll
      for (int n = 0; n < 4; n++)
        b[n] = *(const i32x4*)(bufB + (wn * 64 + n * 16 + frow) * BK + sc);
      __builtin_amdgcn_s_setprio(1);
#pragma unroll
      for (int m = 0; m < 4; m++)
#pragma unroll
        for (int n = 0; n < 4; n++)
          acc[m][n] = __builtin_amdgcn_mfma_i32_16x16x64_i8(a[m], b[n], acc[m][n], 0, 0, 0);
      __builtin_amdgcn_s_setprio(0);
    }
    if (doStage) {
      STAGE_A(t + 2, si, 3); STAGE_B(t + 2, si, 0); STAGE_B(t + 2, si, 1);
    }
    // ---- kk = 1 ----
    {
      const int sc = ((1 * 4 + (lane >> 4)) ^ (lane & 7)) * 16;
      i32x4 a[4], b[4];
#pragma unroll
      for (int m = 0; m < 4; m++)
        a[m] = *(const i32x4*)(bufA + (wm * 64 + m * 16 + frow) * BK + sc);
#pragma unroll
      for (int n = 0; n < 4; n++)
        b[n] = *(const i32x4*)(bufB + (wn * 64 + n * 16 + frow) * BK + sc);
      __builtin_amdgcn_s_setprio(1);
#pragma unroll
      for (int m = 0; m < 4; m++)
#pragma unroll
        for (int n = 0; n < 4; n++)
          acc[m][n] = __builtin_amdgcn_mfma_i32_16x16x64_i8(a[m], b[n], acc[m][n], 0, 0, 0);
      __builtin_amdgcn_s_setprio(0);
    }
    bi = (bi + 1 >= NBUF) ? 0 : bi + 1;
  }
#undef STAGE_A
#undef STAGE_B

  const float dq = scales[2];
#pragma unroll
  for (int m = 0; m < 4; m++) {
#pragma unroll
    for (int n = 0; n < 4; n++) {
      const int row = wm * 64 + m * 16 + (lane >> 4) * 4;
      const int col = wn * 64 + n * 16 + (lane & 15);
#pragma unroll
      for (int j = 0; j < 4; j++) {
        out[(size_t)(brow + row + j) * N_DIM + bcol + col] = (float)acc[m][n][j] * dq;
      }
    }
  }
}

// ============================================================================
extern "C" void kernel_launch(void* const* d_in, const int* in_sizes, int n_in,
                              void* d_out, int out_size, void* d_ws, size_t ws_size,
                              hipStream_t stream) {
  const float* x      = (const float*)d_in[0];   // [1,2048,4096]
  const float* weight = (const float*)d_in[1];   // [4096,4096]
  const float* rms_w  = (const float*)d_in[2];   // [4096]
  float* out = (float*)d_out;

  uint8_t* ws = (uint8_t*)d_ws;
  float* scales   = (float*)(ws + 0);                     // 3 floats
  float* invrms   = (float*)(ws + 64);                    // 8KB
  float* rowmax   = (float*)(ws + 64 + 8192);             // 8KB
  double* partials = (double*)(ws + 64 + 16384);          // 16KB
  char* Aq = (char*)(ws + 65536);                         // 8MB
  char* Bt = (char*)(ws + 65536 + (size_t)M_DIM * K_DIM); // 16MB

  (void)hipFuncSetAttribute((const void*)gemm_kernel,
                            hipFuncAttributeMaxDynamicSharedMemorySize, LDS_BYTES);

  fused_reduce_kernel<<<4096, 256, 0, stream>>>(x, rms_w, weight, invrms, rowmax, partials);
  scales_kernel<<<1, 256, 0, stream>>>(rowmax, partials, scales);
  fused_quant_kernel<<<6144, 256, 0, stream>>>(x, rms_w, invrms, scales, weight, Aq, Bt);
  gemm_kernel<<<dim3(N_DIM / BN, M_DIM / BM), 512, LDS_BYTES, stream>>>(Aq, Bt, out, scales);
}